// Round 3
// baseline (263.387 us; speedup 1.0000x reference)
//
#include <hip/hip_runtime.h>
#include <math.h>

// Problem constants (match reference)
#define N_ATOMS 768
#define FD 128          // feature width F
#define NRBF 32
#define MAXN 96         // neighbor-list capacity (mean ~26)
#define PG 4            // pairs per group (register-blocked per wave)
#define NWAVE 4         // waves per block

constexpr float  CUT2   = 25.0f;
constexpr float  GAMMA_ = 40.96f;            // 1/(5/32)^2
constexpr float  CSTEP  = 5.0f / 31.0f;      // linspace(0,5,32) step
constexpr double KB_D   = 8.617330337217213e-05;
constexpr double KT_D   = 300.0 * KB_D;
constexpr float  KT_F   = (float)KT_D;
constexpr float  TARGET_KE = (float)(0.5 * 2304.0 * KT_D);
constexpr float  Q0_F   = (float)(2.0 * 2304.0 * KT_D * 400.0);  // Q[0]
constexpr float  QI_F   = (float)(2.0 * KT_D * 400.0);           // Q[1..3]

#define DVDT_OFF 0
#define V_OFF    (3 * N_ATOMS)
#define PETA_OFF (6 * N_ATOMS)

// ---------------------------------------------------------------- prep + neighbor list
__global__ __launch_bounds__(256) void prep_nbr_kernel(
    const float* __restrict__ q, const int* __restrict__ z,
    const float* __restrict__ embed, const float* __restrict__ W2,
    const float* __restrict__ W3,
    float* __restrict__ h, float* __restrict__ W2T, float* __restrict__ W3T,
    float* __restrict__ f_acc, int* __restrict__ nbr_cnt, int* __restrict__ nbr_idx)
{
    __shared__ int c;
    int i = blockIdx.x, t = threadIdx.x;
    if (t == 0) c = 0;
    __syncthreads();
    float qx = q[i*3], qy = q[i*3+1], qz = q[i*3+2];
    for (int j = t; j < N_ATOMS; j += 256) {
        if (j == i) continue;
        float dx = qx - q[j*3], dy = qy - q[j*3+1], dz = qz - q[j*3+2];
        float d2 = dx*dx + dy*dy + dz*dz;
        if (d2 < CUT2) {
            int p = atomicAdd(&c, 1);
            if (p < MAXN) nbr_idx[i * MAXN + p] = j;
        }
    }
    int g = i * 256 + t;
    if (g < N_ATOMS * FD) h[g] = embed[z[g >> 7] * FD + (g & 127)];
    int g2 = g - N_ATOMS * FD;
    if (g2 >= 0 && g2 < FD * FD) {
        int r = g2 >> 7, cc = g2 & 127;
        W2T[cc * FD + r] = W2[g2];
        W3T[cc * FD + r] = W3[g2];
    }
    if (g < 3 * N_ATOMS) f_acc[g] = 0.f;
    __syncthreads();
    if (t == 0) nbr_cnt[i] = min(c, MAXN);
}

// ---------------------------------------------------------------- forward + mbar
// Block = atom i, 4 waves, wave-synchronous inner loop (no __syncthreads).
// Lane owns features f0=2*lane, f0+1. W1 in LDS (frees 64 VGPRs), W2 rows
// streamed from global (L2-hot, amortized over PG pairs). All per-pair
// geometry is wave-uniform -> scalarized (s_loads, SGPR predicates).
__global__ __launch_bounds__(256, 3) void fwd_kernel(
    const float* __restrict__ q, const float* __restrict__ W1,
    const float* __restrict__ b1, const float* __restrict__ W2,
    const float* __restrict__ b2, const float* __restrict__ h,
    const float* __restrict__ W3, const float* __restrict__ W3T,
    const float* __restrict__ wout,
    const int* __restrict__ nbr_cnt, const int* __restrict__ nbr_idx,
    float* __restrict__ mbar)
{
    __shared__ float W1s[NRBF * FD];         // 16384 B
    __shared__ float scr[NWAVE * 640];       // per wave: rbf[4][32], a1[4][128]
    __shared__ float red[NWAVE * FD];        // cross-wave m partials

    int t = threadIdx.x, wave = t >> 6, lane = t & 63, i = blockIdx.x;
    int f0 = 2 * lane;

    for (int r = t; r < NRBF * FD / 4; r += 256)
        ((float4*)W1s)[r] = ((const float4*)W1)[r];

    float2 b1v = *(const float2*)(b1 + f0);
    float2 b2v = *(const float2*)(b2 + f0);
    int cnt = nbr_cnt[i];
    const int* nlist = nbr_idx + i * MAXN;
    float* ws  = scr + wave * 640;
    float* a1s = ws + 128;
    float qx = q[i*3], qy = q[i*3+1], qz = q[i*3+2];
    __syncthreads();   // W1s ready

    float macc0 = 0.f, macc1 = 0.f;
    int ngroups = (cnt + PG - 1) / PG;

    for (int g = wave; g < ngroups; g += NWAVE) {
        int base = g * PG;
        float dd[PG]; float2 hj[PG]; bool valp[PG];
#pragma unroll
        for (int p = 0; p < PG; p++) {
            int idx = base + p;
            valp[p] = idx < cnt;                               // uniform
            int j = __builtin_amdgcn_readfirstlane(nlist[valp[p] ? idx : cnt - 1]);
            float dx = qx - q[j*3], dy = qy - q[j*3+1], dz = qz - q[j*3+2];
            dd[p] = sqrtf(dx*dx + dy*dy + dz*dz);
            hj[p] = *(const float2*)(h + j * FD + f0);
        }
        // rbf: lane covers (p = lane>>4, k = 2*lane & 31) and k+1
        {
            int p = lane >> 4; int k = (2 * lane) & 31;
            float dsel = dd[p];                                // small select chain
            float u0 = dsel - CSTEP * (float)k;
            float u1u = dsel - CSTEP * (float)(k + 1);
            float2 rv; rv.x = __expf(-GAMMA_ * u0 * u0); rv.y = __expf(-GAMMA_ * u1u * u1u);
            *(float2*)(ws + 2 * lane) = rv;
        }
        __builtin_amdgcn_wave_barrier();
        // u1 = b1 + rbf @ W1 (W1 from LDS, lane-strided float2 = 2-way, free)
        float u1a[PG], u1b[PG];
#pragma unroll
        for (int p = 0; p < PG; p++) { u1a[p] = b1v.x; u1b[p] = b1v.y; }
#pragma unroll
        for (int k4 = 0; k4 < NRBF / 4; k4++) {
            float2 w0 = *(const float2*)(W1s + (k4*4+0) * FD + f0);
            float2 w1v = *(const float2*)(W1s + (k4*4+1) * FD + f0);
            float2 w2v = *(const float2*)(W1s + (k4*4+2) * FD + f0);
            float2 w3v = *(const float2*)(W1s + (k4*4+3) * FD + f0);
#pragma unroll
            for (int p = 0; p < PG; p++) {
                float4 r = *(const float4*)(ws + p * 32 + k4 * 4);
                u1a[p] += r.x*w0.x + r.y*w1v.x + r.z*w2v.x + r.w*w3v.x;
                u1b[p] += r.x*w0.y + r.y*w1v.y + r.z*w2v.y + r.w*w3v.y;
            }
        }
#pragma unroll
        for (int p = 0; p < PG; p++) {
            float2 a; a.x = fmaxf(u1a[p], 0.f); a.y = fmaxf(u1b[p], 0.f);
            *(float2*)(a1s + p * FD + f0) = a;
        }
        __builtin_amdgcn_wave_barrier();
        // filt = a1 @ W2 (+b2): W2 rows from global (L2), a1 via LDS broadcast
        float dota[PG] = {0,0,0,0}, dotb[PG] = {0,0,0,0};
#pragma unroll 4
        for (int c4 = 0; c4 < FD / 4; c4++) {
            float2 w0 = *(const float2*)(W2 + (c4*4+0) * FD + f0);
            float2 w1v = *(const float2*)(W2 + (c4*4+1) * FD + f0);
            float2 w2v = *(const float2*)(W2 + (c4*4+2) * FD + f0);
            float2 w3v = *(const float2*)(W2 + (c4*4+3) * FD + f0);
#pragma unroll
            for (int p = 0; p < PG; p++) {
                float4 a = *(const float4*)(a1s + p * FD + c4 * 4);
                dota[p] += a.x*w0.x + a.y*w1v.x + a.z*w2v.x + a.w*w3v.x;
                dotb[p] += a.x*w0.y + a.y*w1v.y + a.z*w2v.y + a.w*w3v.y;
            }
        }
#pragma unroll
        for (int p = 0; p < PG; p++) {
            if (valp[p]) {                                     // uniform branch
                macc0 += (dota[p] + b2v.x) * hj[p].x;
                macc1 += (dotb[p] + b2v.y) * hj[p].y;
            }
        }
    }
    red[wave * FD + f0]     = macc0;
    red[wave * FD + f0 + 1] = macc1;
    __syncthreads();
    // ---- mbar epilogue (threads 0..127; scr reused post-barrier) ----
    if (t < FD) {
        float mf = red[t] + red[FD + t] + red[2*FD + t] + red[3*FD + t];
        scr[t] = mf;
    }
    __syncthreads();
    if (t < FD) {
        float acc = 0.f;
#pragma unroll 4
        for (int c4 = 0; c4 < FD / 4; c4++) {
            float4 m4 = *(const float4*)(scr + c4 * 4);
            acc += m4.x * W3[(c4*4+0)*FD + t] + m4.y * W3[(c4*4+1)*FD + t]
                 + m4.z * W3[(c4*4+2)*FD + t] + m4.w * W3[(c4*4+3)*FD + t];
        }
        scr[FD + t] = (acc > 0.f) ? wout[t] : 0.f;
    }
    __syncthreads();
    if (t < FD) {
        float mb = 0.f;
#pragma unroll 4
        for (int c4 = 0; c4 < FD / 4; c4++) {
            float4 g4 = *(const float4*)(scr + FD + c4 * 4);
            mb += g4.x * W3T[(c4*4+0)*FD + t] + g4.y * W3T[(c4*4+1)*FD + t]
                + g4.z * W3T[(c4*4+2)*FD + t] + g4.w * W3T[(c4*4+3)*FD + t];
        }
        mbar[i * FD + t] = mb;
    }
}

// ---------------------------------------------------------------- backward + force atomics
__global__ __launch_bounds__(256, 3) void bwd_kernel(
    const float* __restrict__ q, const float* __restrict__ W1,
    const float* __restrict__ b1, const float* __restrict__ W2T,
    const float* __restrict__ h, const float* __restrict__ mbar,
    const int* __restrict__ nbr_cnt, const int* __restrict__ nbr_idx,
    float* __restrict__ f_acc)
{
    __shared__ float W1s[NRBF * FD];         // 16384 B
    __shared__ float scr[NWAVE * 768];       // per wave: rbf[128], crbf[128], t[4][128]

    int t = threadIdx.x, wave = t >> 6, lane = t & 63, i = blockIdx.x;
    int f0 = 2 * lane;

    for (int r = t; r < NRBF * FD / 4; r += 256)
        ((float4*)W1s)[r] = ((const float4*)W1)[r];

    float2 b1v = *(const float2*)(b1 + f0);
    float2 mb  = *(const float2*)(mbar + i * FD + f0);
    int cnt = nbr_cnt[i];
    const int* nlist = nbr_idx + i * MAXN;
    float* rbfs  = scr + wave * 768;
    float* crbfs = rbfs + 128;
    float* ts    = crbfs + 128;
    float qx = q[i*3], qy = q[i*3+1], qz = q[i*3+2];
    __syncthreads();

    int ngroups = (cnt + PG - 1) / PG;

    for (int g = wave; g < ngroups; g += NWAVE) {
        int base = g * PG;
        int js[PG]; float dd[PG]; bool valp[PG];
#pragma unroll
        for (int p = 0; p < PG; p++) {
            int idx = base + p;
            valp[p] = idx < cnt;                               // uniform
            int j = __builtin_amdgcn_readfirstlane(nlist[valp[p] ? idx : cnt - 1]);
            js[p] = j;
            float dx = qx - q[j*3], dy = qy - q[j*3+1], dz = qz - q[j*3+2];
            dd[p] = sqrtf(dx*dx + dy*dy + dz*dz);
            float2 hj = *(const float2*)(h + j * FD + f0);
            float2 tv; tv.x = mb.x * hj.x; tv.y = mb.y * hj.y; // dE/dfilt
            *(float2*)(ts + p * FD + f0) = tv;
        }
        {
            int p = lane >> 4; int k = (2 * lane) & 31;
            float dsel = dd[p];
            float u0 = dsel - CSTEP * (float)k;
            float u1u = dsel - CSTEP * (float)(k + 1);
            float r0 = __expf(-GAMMA_ * u0 * u0), r1 = __expf(-GAMMA_ * u1u * u1u);
            float2 rv;  rv.x = r0;                       rv.y = r1;
            float2 cv;  cv.x = -2.f * GAMMA_ * u0 * r0;  cv.y = -2.f * GAMMA_ * u1u * r1;
            *(float2*)(rbfs  + 2 * lane) = rv;
            *(float2*)(crbfs + 2 * lane) = cv;
        }
        __builtin_amdgcn_wave_barrier();
        // u1 (gate) and ef = crbf @ W1 (W1 from LDS)
        float u1a[PG], u1b[PG], efa[PG], efb[PG];
#pragma unroll
        for (int p = 0; p < PG; p++) { u1a[p] = b1v.x; u1b[p] = b1v.y; efa[p] = 0.f; efb[p] = 0.f; }
#pragma unroll
        for (int k4 = 0; k4 < NRBF / 4; k4++) {
            float2 w0 = *(const float2*)(W1s + (k4*4+0) * FD + f0);
            float2 w1v = *(const float2*)(W1s + (k4*4+1) * FD + f0);
            float2 w2v = *(const float2*)(W1s + (k4*4+2) * FD + f0);
            float2 w3v = *(const float2*)(W1s + (k4*4+3) * FD + f0);
#pragma unroll
            for (int p = 0; p < PG; p++) {
                float4 r = *(const float4*)(rbfs  + p * 32 + k4 * 4);
                float4 c = *(const float4*)(crbfs + p * 32 + k4 * 4);
                u1a[p] += r.x*w0.x + r.y*w1v.x + r.z*w2v.x + r.w*w3v.x;
                u1b[p] += r.x*w0.y + r.y*w1v.y + r.z*w2v.y + r.w*w3v.y;
                efa[p] += c.x*w0.x + c.y*w1v.x + c.z*w2v.x + c.w*w3v.x;
                efb[p] += c.x*w0.y + c.y*w1v.y + c.z*w2v.y + c.w*w3v.y;
            }
        }
        // du1 = gate .* (t @ W2T): W2T rows from global (L2), t via LDS broadcast
        float dota[PG] = {0,0,0,0}, dotb[PG] = {0,0,0,0};
#pragma unroll 4
        for (int c4 = 0; c4 < FD / 4; c4++) {
            float2 w0 = *(const float2*)(W2T + (c4*4+0) * FD + f0);
            float2 w1v = *(const float2*)(W2T + (c4*4+1) * FD + f0);
            float2 w2v = *(const float2*)(W2T + (c4*4+2) * FD + f0);
            float2 w3v = *(const float2*)(W2T + (c4*4+3) * FD + f0);
#pragma unroll
            for (int p = 0; p < PG; p++) {
                float4 a = *(const float4*)(ts + p * FD + c4 * 4);
                dota[p] += a.x*w0.x + a.y*w1v.x + a.z*w2v.x + a.w*w3v.x;
                dotb[p] += a.x*w0.y + a.y*w1v.y + a.z*w2v.y + a.w*w3v.y;
            }
        }
        float s[PG];
#pragma unroll
        for (int p = 0; p < PG; p++) {
            float da = (u1a[p] > 0.f) ? dota[p] : 0.f;
            float db = (u1b[p] > 0.f) ? dotb[p] : 0.f;
            s[p] = da * efa[p] + db * efb[p];
        }
#pragma unroll
        for (int off = 1; off < 64; off <<= 1) {
#pragma unroll
            for (int p = 0; p < PG; p++) s[p] += __shfl_xor(s[p], off, 64);
        }
        // atomic tail: per-p uniform code, lane==p predication (no dynamic
        // indexing -> no scratch). Geometry recomputed from scalar q loads.
#pragma unroll
        for (int p = 0; p < PG; p++) {
            if (valp[p] && lane == p) {
                int j = js[p];
                float dx = qx - q[j*3], dy = qy - q[j*3+1], dz = qz - q[j*3+2];
                float coef = s[p] / dd[p];
                float fx = coef * dx, fy = coef * dy, fz = coef * dz;
                atomicAdd(f_acc + i*3 + 0, -fx);
                atomicAdd(f_acc + i*3 + 1, -fy);
                atomicAdd(f_acc + i*3 + 2, -fz);
                atomicAdd(f_acc + j*3 + 0, fx);
                atomicAdd(f_acc + j*3 + 1, fy);
                atomicAdd(f_acc + j*3 + 2, fz);
            }
        }
    }
}

// ---------------------------------------------------------------- finalize: dvdt, v, KE, dpeta
__global__ __launch_bounds__(256) void fin_kernel(
    const float* __restrict__ v, const float* __restrict__ mass,
    const float* __restrict__ p_eta, const float* __restrict__ f_acc,
    float* __restrict__ out)
{
    __shared__ float red[256];
    int t = threadIdx.x;
    float ke = 0.f;
    float c = p_eta[0] / Q0_F;
    for (int idx = t; idx < 3 * N_ATOMS; idx += 256) {
        int a = idx / 3;
        float vv = v[idx], mi = mass[a];
        out[DVDT_OFF + idx] = (f_acc[idx] - c * vv * mi) / mi;
        out[V_OFF + idx] = vv;
        ke += 0.5f * mi * vv * vv;
    }
    red[t] = ke;
    __syncthreads();
    for (int s = 128; s > 0; s >>= 1) {
        if (t < s) red[t] += red[t + s];
        __syncthreads();
    }
    if (t == 0) {
        float k0 = red[0];
        float e0 = p_eta[0], e1 = p_eta[1], e2 = p_eta[2], e3 = p_eta[3];
        out[PETA_OFF + 0] = 2.f * (k0 - TARGET_KE) - e0 * e1 / QI_F;
        out[PETA_OFF + 1] = e0 * e0 / Q0_F - KT_F - e1 * e2 / QI_F;
        out[PETA_OFF + 2] = e1 * e1 / QI_F - KT_F - e2 * e3 / QI_F;
        out[PETA_OFF + 3] = e2 * e2 / QI_F - KT_F;
    }
}

// ---------------------------------------------------------------- launch
extern "C" void kernel_launch(void* const* d_in, const int* in_sizes, int n_in,
                              void* d_out, int out_size, void* d_ws, size_t ws_size,
                              hipStream_t stream)
{
    const float* v     = (const float*)d_in[0];
    const float* q     = (const float*)d_in[1];
    const float* p_eta = (const float*)d_in[2];
    const float* mass  = (const float*)d_in[3];
    const float* embed = (const float*)d_in[4];
    const float* W1    = (const float*)d_in[5];
    const float* b1    = (const float*)d_in[6];
    const float* W2    = (const float*)d_in[7];
    const float* b2    = (const float*)d_in[8];
    const float* W3    = (const float*)d_in[9];
    const float* wout  = (const float*)d_in[10];
    const int*   z     = (const int*)d_in[11];
    float* out = (float*)d_out;

    float* h     = (float*)d_ws;            // 98304
    float* W2T   = h + N_ATOMS * FD;        // 16384
    float* W3T   = W2T + FD * FD;           // 16384
    float* mbar  = W3T + FD * FD;           // 98304
    float* f_acc = mbar + N_ATOMS * FD;     // 2304
    int* nbr_cnt = (int*)(f_acc + 3 * N_ATOMS);  // 768
    int* nbr_idx = nbr_cnt + N_ATOMS;            // 768*96

    prep_nbr_kernel<<<N_ATOMS, 256, 0, stream>>>(q, z, embed, W2, W3, h, W2T,
                                                 W3T, f_acc, nbr_cnt, nbr_idx);
    fwd_kernel<<<N_ATOMS, 256, 0, stream>>>(q, W1, b1, W2, b2, h, W3, W3T,
                                            wout, nbr_cnt, nbr_idx, mbar);
    bwd_kernel<<<N_ATOMS, 256, 0, stream>>>(q, W1, b1, W2T, h, mbar,
                                            nbr_cnt, nbr_idx, f_acc);
    fin_kernel<<<1, 256, 0, stream>>>(v, mass, p_eta, f_acc, out);
}

// Round 4
// 245.020 us; speedup vs baseline: 1.0750x; 1.0750x over previous
//
#include <hip/hip_runtime.h>
#include <math.h>

// Problem constants (match reference)
#define N_ATOMS 768
#define FD 128          // feature width F
#define NRBF 32
#define MAXN 96         // neighbor-list capacity (mean ~26)
#define PG 4            // pairs per group (amortizes W2 LDS reads)
#define NWAVE 4         // waves per block

constexpr float  CUT2   = 25.0f;
constexpr float  GAMMA_ = 40.96f;            // 1/(5/32)^2
constexpr float  CSTEP  = 5.0f / 31.0f;      // linspace(0,5,32) step
constexpr double KB_D   = 8.617330337217213e-05;
constexpr double KT_D   = 300.0 * KB_D;
constexpr float  KT_F   = (float)KT_D;
constexpr float  TARGET_KE = (float)(0.5 * 2304.0 * KT_D);
constexpr float  Q0_F   = (float)(2.0 * 2304.0 * KT_D * 400.0);  // Q[0]
constexpr float  QI_F   = (float)(2.0 * KT_D * 400.0);           // Q[1..3]

#define DVDT_OFF 0
#define V_OFF    (3 * N_ATOMS)
#define PETA_OFF (6 * N_ATOMS)

// Granule-rotated W2 LDS layout: row c, 16B-granule g (g = f/4) stored at
// float index c*128 + ((g+c)&31)*4.  Row reads (fixed c, g=s) and column
// reads (fixed g=lane, c=r) are BOTH conflict-free b128.
#define ROT(c, g) (((c) << 7) + ((((g) + (c)) & 31) << 2))

// select wave-uniform per-p scalar by lane-varying p (no array indexing -> no scratch)
#define SEL4(p, a0, a1, a2, a3) (((p) & 1) ? (((p) & 2) ? (a3) : (a1)) : (((p) & 2) ? (a2) : (a0)))
#define F4C(v, p) ((p) == 0 ? (v).x : (p) == 1 ? (v).y : (p) == 2 ? (v).z : (v).w)

// ---------------------------------------------------------------- prep + neighbor list
__global__ __launch_bounds__(256) void prep_nbr_kernel(
    const float* __restrict__ q, const int* __restrict__ z,
    const float* __restrict__ embed, const float* __restrict__ W3,
    float* __restrict__ h, float* __restrict__ W3T,
    float* __restrict__ f_acc, int* __restrict__ nbr_cnt, int* __restrict__ nbr_idx)
{
    __shared__ int c;
    int i = blockIdx.x, t = threadIdx.x;
    if (t == 0) c = 0;
    __syncthreads();
    float qx = q[i*3], qy = q[i*3+1], qz = q[i*3+2];
    for (int j = t; j < N_ATOMS; j += 256) {
        if (j == i) continue;
        float dx = qx - q[j*3], dy = qy - q[j*3+1], dz = qz - q[j*3+2];
        float d2 = dx*dx + dy*dy + dz*dz;
        if (d2 < CUT2) {
            int p = atomicAdd(&c, 1);
            if (p < MAXN) nbr_idx[i * MAXN + p] = j;
        }
    }
    int g = i * 256 + t;
    if (g < N_ATOMS * FD) h[g] = embed[z[g >> 7] * FD + (g & 127)];
    int g2 = g - N_ATOMS * FD;
    if (g2 >= 0 && g2 < FD * FD) {
        int r = g2 >> 7, cc = g2 & 127;
        W3T[cc * FD + r] = W3[g2];
    }
    if (g < 3 * N_ATOMS) f_acc[g] = 0.f;
    __syncthreads();
    if (t == 0) nbr_cnt[i] = min(c, MAXN);
}

// ---------------------------------------------------------------- merged SchNet fwd+bwd
// Block = atom i, 4 waves split the pair list in groups of PG=4.
// Phase F: m_i accumulation (filt = relu(rbf@W1+b1)@W2+b2, m += filt*h_j)
// Epilogue: mbar_i = W3 @ (wout * gate(m_i@W3))  (per-atom local!)
// Phase B: s_ij = sum_c gate(u1_c)*du1_c*ef_c, force scatter via atomics.
// W2 LDS-resident (rotated). Per-wave scratch, no inner-loop __syncthreads.
__global__ __launch_bounds__(256, 2) void schnet_kernel(
    const float* __restrict__ q, const float* __restrict__ W1,
    const float* __restrict__ b1, const float* __restrict__ W2,
    const float* __restrict__ b2, const float* __restrict__ h,
    const float* __restrict__ W3, const float* __restrict__ W3T,
    const float* __restrict__ wout,
    const int* __restrict__ nbr_cnt, const int* __restrict__ nbr_idx,
    float* __restrict__ f_acc)
{
    __shared__ float W2s[FD * FD];           // 65536 B, rotated layout
    __shared__ float rbfw[NWAVE * 256];      // per wave: rbf[4][32] | crbf[4][32]
    __shared__ float a1w[NWAVE * 512];       // per wave: a1s/ts [c or f][p] (128x4)
    __shared__ float red[512];               // cross-wave m partials / m / gb
    __shared__ float mbs[FD];                // mbar_i

    int t = threadIdx.x, wave = t >> 6, lane = t & 63, i = blockIdx.x;
    int c0 = lane, c1 = lane + 64;           // owned contraction rows
    int f4 = 4 * (lane & 31);                // owned feature granule
    int half = lane >> 5;

    // ---- stage W2 rotated (coalesced b128 read, conflict-spread b128 write)
    for (int task = t; task < FD * 32; task += 256) {
        int c = task >> 5, g = task & 31;
        *(float4*)(W2s + ROT(c, g)) = *(const float4*)(W2 + c * FD + 4 * g);
    }
    // ---- W1 columns c0,c1 into registers (64 VGPR)
    float w1c0[NRBF], w1c1[NRBF];
#pragma unroll
    for (int k = 0; k < NRBF; k++) {
        w1c0[k] = W1[k * FD + c0];
        w1c1[k] = W1[k * FD + c1];
    }
    float b1c0 = b1[c0], b1c1 = b1[c1];
    float4 b2v = *(const float4*)(b2 + f4);
    int cnt = nbr_cnt[i];
    const int* nlist = nbr_idx + i * MAXN;
    float qx = q[i*3], qy = q[i*3+1], qz = q[i*3+2];
    float* rbf_s = rbfw + wave * 256;        // [p*32+k]; crbf at +128
    float* a1s   = a1w + wave * 512;         // [(c or f)*4 + p]
    int ngroups = (cnt + PG - 1) / PG;
    __syncthreads();                          // W2s ready

    // ================= Phase F: forward =================
    float macc0 = 0.f, macc1 = 0.f, macc2 = 0.f, macc3 = 0.f;
    for (int g = wave; g < ngroups; g += NWAVE) {
        int base = g * PG;
        int j0, j1, j2, j3; float dd0, dd1, dd2, dd3; bool v0, v1, v2, v3;
        float4 hj0, hj1, hj2, hj3;
#define GEO(p, jp, ddp, vp, hjp)                                              \
        {   int idx = base + p; vp = idx < cnt;                               \
            jp = __builtin_amdgcn_readfirstlane(nlist[vp ? idx : cnt - 1]);   \
            float dx = qx - q[jp*3], dy = qy - q[jp*3+1], dz = qz - q[jp*3+2];\
            ddp = sqrtf(dx*dx + dy*dy + dz*dz);                               \
            hjp = *(const float4*)(h + jp * FD + f4); }
        GEO(0, j0, dd0, v0, hj0) GEO(1, j1, dd1, v1, hj1)
        GEO(2, j2, dd2, v2, hj2) GEO(3, j3, dd3, v3, hj3)
#undef GEO
        // rbf: lanes 0..31, p = lane>>3, k4 = (lane&7)*4
        if (lane < 32) {
            int p = lane >> 3, k4 = (lane & 7) * 4;
            float d = SEL4(p, dd0, dd1, dd2, dd3);
            float4 rv;
            { float u = d - CSTEP*(float)(k4+0); rv.x = __expf(-GAMMA_*u*u); }
            { float u = d - CSTEP*(float)(k4+1); rv.y = __expf(-GAMMA_*u*u); }
            { float u = d - CSTEP*(float)(k4+2); rv.z = __expf(-GAMMA_*u*u); }
            { float u = d - CSTEP*(float)(k4+3); rv.w = __expf(-GAMMA_*u*u); }
            *(float4*)(rbf_s + p * 32 + k4) = rv;
        }
        __builtin_amdgcn_wave_barrier();
        // u1[p][c0,c1] = b1 + rbf@W1
        float u10[PG], u11[PG];
#pragma unroll
        for (int p = 0; p < PG; p++) { u10[p] = b1c0; u11[p] = b1c1; }
#pragma unroll
        for (int k4 = 0; k4 < NRBF / 4; k4++) {
#pragma unroll
            for (int p = 0; p < PG; p++) {
                float4 r = *(const float4*)(rbf_s + p * 32 + k4 * 4);   // bcast
                u10[p] += r.x*w1c0[k4*4] + r.y*w1c0[k4*4+1] + r.z*w1c0[k4*4+2] + r.w*w1c0[k4*4+3];
                u11[p] += r.x*w1c1[k4*4] + r.y*w1c1[k4*4+1] + r.z*w1c1[k4*4+2] + r.w*w1c1[k4*4+3];
            }
        }
        {   // a1s[c][p] writes: granules c0, c1 -> conflict-free b128
            float4 a0 = make_float4(fmaxf(u10[0],0.f), fmaxf(u10[1],0.f),
                                    fmaxf(u10[2],0.f), fmaxf(u10[3],0.f));
            float4 a1v = make_float4(fmaxf(u11[0],0.f), fmaxf(u11[1],0.f),
                                     fmaxf(u11[2],0.f), fmaxf(u11[3],0.f));
            *(float4*)(a1s + c0 * 4) = a0;
            *(float4*)(a1s + c1 * 4) = a1v;
        }
        __builtin_amdgcn_wave_barrier();
        // filt dot: lane owns f4 (4 features), halves split rows
        float dot[PG][4];
#pragma unroll
        for (int p = 0; p < PG; p++) { dot[p][0]=0; dot[p][1]=0; dot[p][2]=0; dot[p][3]=0; }
#pragma unroll 8
        for (int s = 0; s < 64; s++) {
            int r = 2 * s + half;
            float4 w = *(const float4*)(W2s + ROT(r, lane & 31));  // conflict-free
            float4 a = *(const float4*)(a1s + r * 4);              // 2-addr multicast
#pragma unroll
            for (int p = 0; p < PG; p++) {
                float ap = F4C(a, p);
                dot[p][0] += ap * w.x; dot[p][1] += ap * w.y;
                dot[p][2] += ap * w.z; dot[p][3] += ap * w.w;
            }
        }
#pragma unroll
        for (int p = 0; p < PG; p++)
#pragma unroll
            for (int e = 0; e < 4; e++)
                dot[p][e] += __shfl_xor(dot[p][e], 32, 64);
#define MACC(p, vp, hjp)                                                      \
        if (vp) { macc0 += (dot[p][0] + b2v.x) * hjp.x;                       \
                  macc1 += (dot[p][1] + b2v.y) * hjp.y;                       \
                  macc2 += (dot[p][2] + b2v.z) * hjp.z;                       \
                  macc3 += (dot[p][3] + b2v.w) * hjp.w; }
        MACC(0, v0, hj0) MACC(1, v1, hj1) MACC(2, v2, hj2) MACC(3, v3, hj3)
#undef MACC
        __builtin_amdgcn_wave_barrier();     // protect scratch before next group
    }
    if (half == 0)
        *(float4*)(red + wave * FD + f4) = make_float4(macc0, macc1, macc2, macc3);
    __syncthreads();

    // ================= Epilogue: mbar (threads 0..127) =================
    if (t < FD) red[t] = red[t] + red[FD + t] + red[2*FD + t] + red[3*FD + t];  // m
    __syncthreads();
    if (t < FD) {
        float g3 = 0.f;
#pragma unroll 8
        for (int c4 = 0; c4 < FD / 4; c4++) {
            float4 m4 = *(const float4*)(red + c4 * 4);
            g3 += m4.x * W3[(c4*4+0)*FD + t] + m4.y * W3[(c4*4+1)*FD + t]
                + m4.z * W3[(c4*4+2)*FD + t] + m4.w * W3[(c4*4+3)*FD + t];
        }
        red[FD + t] = (g3 > 0.f) ? wout[t] : 0.f;   // gb
    }
    __syncthreads();
    if (t < FD) {
        float mb = 0.f;
#pragma unroll 8
        for (int c4 = 0; c4 < FD / 4; c4++) {
            float4 g4 = *(const float4*)(red + FD + c4 * 4);
            mb += g4.x * W3T[(c4*4+0)*FD + t] + g4.y * W3T[(c4*4+1)*FD + t]
                + g4.z * W3T[(c4*4+2)*FD + t] + g4.w * W3T[(c4*4+3)*FD + t];
        }
        mbs[t] = mb;
    }
    __syncthreads();
    float mb0 = mbs[c0], mb1 = mbs[c1];

    // ================= Phase B: backward =================
    for (int g = wave; g < ngroups; g += NWAVE) {
        int base = g * PG;
        int j0, j1, j2, j3; bool v0, v1, v2, v3;
        float dd0, dd1, dd2, dd3;
        float dx0, dy0, dz0, dx1, dy1, dz1, dx2, dy2, dz2, dx3, dy3, dz3;
#define GEOB(p, jp, ddp, vp, dxp, dyp, dzp)                                   \
        {   int idx = base + p; vp = idx < cnt;                               \
            jp = __builtin_amdgcn_readfirstlane(nlist[vp ? idx : cnt - 1]);   \
            dxp = qx - q[jp*3]; dyp = qy - q[jp*3+1]; dzp = qz - q[jp*3+2];   \
            ddp = sqrtf(dxp*dxp + dyp*dyp + dzp*dzp); }
        GEOB(0, j0, dd0, v0, dx0, dy0, dz0) GEOB(1, j1, dd1, v1, dx1, dy1, dz1)
        GEOB(2, j2, dd2, v2, dx2, dy2, dz2) GEOB(3, j3, dd3, v3, dx3, dy3, dz3)
#undef GEOB
        // ts[f][p] = mbar_f * h_j,f ; lane stages f=c0 and f=c1 rows
        {
            float4 t0 = make_float4(mb0 * h[j0*FD + c0], mb0 * h[j1*FD + c0],
                                    mb0 * h[j2*FD + c0], mb0 * h[j3*FD + c0]);
            float4 t1 = make_float4(mb1 * h[j0*FD + c1], mb1 * h[j1*FD + c1],
                                    mb1 * h[j2*FD + c1], mb1 * h[j3*FD + c1]);
            *(float4*)(a1s + c0 * 4) = t0;
            *(float4*)(a1s + c1 * 4) = t1;
        }
        // rbf + crbf
        if (lane < 32) {
            int p = lane >> 3, k4 = (lane & 7) * 4;
            float d = SEL4(p, dd0, dd1, dd2, dd3);
            float4 rv, cv;
            { float u = d - CSTEP*(float)(k4+0); rv.x = __expf(-GAMMA_*u*u); cv.x = -2.f*GAMMA_*u*rv.x; }
            { float u = d - CSTEP*(float)(k4+1); rv.y = __expf(-GAMMA_*u*u); cv.y = -2.f*GAMMA_*u*rv.y; }
            { float u = d - CSTEP*(float)(k4+2); rv.z = __expf(-GAMMA_*u*u); cv.z = -2.f*GAMMA_*u*rv.z; }
            { float u = d - CSTEP*(float)(k4+3); rv.w = __expf(-GAMMA_*u*u); cv.w = -2.f*GAMMA_*u*rv.w; }
            *(float4*)(rbf_s + p * 32 + k4) = rv;
            *(float4*)(rbf_s + 128 + p * 32 + k4) = cv;
        }
        __builtin_amdgcn_wave_barrier();
        // u1 (gate) and ef for rows c0,c1
        float u10[PG], u11[PG], ef0[PG], ef1[PG];
#pragma unroll
        for (int p = 0; p < PG; p++) { u10[p] = b1c0; u11[p] = b1c1; ef0[p] = 0.f; ef1[p] = 0.f; }
#pragma unroll
        for (int k4 = 0; k4 < NRBF / 4; k4++) {
#pragma unroll
            for (int p = 0; p < PG; p++) {
                float4 r = *(const float4*)(rbf_s + p * 32 + k4 * 4);
                float4 cdr = *(const float4*)(rbf_s + 128 + p * 32 + k4 * 4);
                u10[p] += r.x*w1c0[k4*4] + r.y*w1c0[k4*4+1] + r.z*w1c0[k4*4+2] + r.w*w1c0[k4*4+3];
                u11[p] += r.x*w1c1[k4*4] + r.y*w1c1[k4*4+1] + r.z*w1c1[k4*4+2] + r.w*w1c1[k4*4+3];
                ef0[p] += cdr.x*w1c0[k4*4] + cdr.y*w1c0[k4*4+1] + cdr.z*w1c0[k4*4+2] + cdr.w*w1c0[k4*4+3];
                ef1[p] += cdr.x*w1c1[k4*4] + cdr.y*w1c1[k4*4+1] + cdr.z*w1c1[k4*4+2] + cdr.w*w1c1[k4*4+3];
            }
        }
        // du1[c] = sum_f W2[c,f] t_f : lane reads rows c0,c1 (conflict-free)
        float du0[PG] = {0,0,0,0}, du1v[PG] = {0,0,0,0};
#pragma unroll 8
        for (int s = 0; s < 32; s++) {
            float4 w0 = *(const float4*)(W2s + ROT(c0, s));
            float4 w1r = *(const float4*)(W2s + ROT(c1, s));
            float4 tA = *(const float4*)(a1s + (4*s+0) * 4);   // bcast
            float4 tB = *(const float4*)(a1s + (4*s+1) * 4);
            float4 tC = *(const float4*)(a1s + (4*s+2) * 4);
            float4 tD = *(const float4*)(a1s + (4*s+3) * 4);
#pragma unroll
            for (int p = 0; p < PG; p++) {
                du0[p]  += w0.x*F4C(tA,p) + w0.y*F4C(tB,p) + w0.z*F4C(tC,p) + w0.w*F4C(tD,p);
                du1v[p] += w1r.x*F4C(tA,p) + w1r.y*F4C(tB,p) + w1r.z*F4C(tC,p) + w1r.w*F4C(tD,p);
            }
        }
        // s_ij partials and wave reduction
        float s0, s1, s2, s3;
#define COMB(p, sp) sp = ((u10[p] > 0.f) ? du0[p] : 0.f) * ef0[p]             \
                       + ((u11[p] > 0.f) ? du1v[p] : 0.f) * ef1[p];
        COMB(0, s0) COMB(1, s1) COMB(2, s2) COMB(3, s3)
#undef COMB
#pragma unroll
        for (int off = 1; off < 64; off <<= 1) {
            s0 += __shfl_xor(s0, off, 64);
            s1 += __shfl_xor(s1, off, 64);
            s2 += __shfl_xor(s2, off, 64);
            s3 += __shfl_xor(s3, off, 64);
        }
#define TAIL(p, vp, jp, sp, ddp, dxp, dyp, dzp)                               \
        if (vp && lane == p) {                                                \
            float coef = sp / ddp;                                            \
            float fx = coef * dxp, fy = coef * dyp, fz = coef * dzp;          \
            atomicAdd(f_acc + i*3 + 0, -fx);                                  \
            atomicAdd(f_acc + i*3 + 1, -fy);                                  \
            atomicAdd(f_acc + i*3 + 2, -fz);                                  \
            atomicAdd(f_acc + jp*3 + 0, fx);                                  \
            atomicAdd(f_acc + jp*3 + 1, fy);                                  \
            atomicAdd(f_acc + jp*3 + 2, fz);                                  \
        }
        TAIL(0, v0, j0, s0, dd0, dx0, dy0, dz0)
        TAIL(1, v1, j1, s1, dd1, dx1, dy1, dz1)
        TAIL(2, v2, j2, s2, dd2, dx2, dy2, dz2)
        TAIL(3, v3, j3, s3, dd3, dx3, dy3, dz3)
#undef TAIL
        __builtin_amdgcn_wave_barrier();
    }
}

// ---------------------------------------------------------------- finalize
__global__ __launch_bounds__(256) void fin_kernel(
    const float* __restrict__ v, const float* __restrict__ mass,
    const float* __restrict__ p_eta, const float* __restrict__ f_acc,
    float* __restrict__ out)
{
    __shared__ float red[256];
    int t = threadIdx.x;
    float ke = 0.f;
    float c = p_eta[0] / Q0_F;
    for (int idx = t; idx < 3 * N_ATOMS; idx += 256) {
        int a = idx / 3;
        float vv = v[idx], mi = mass[a];
        out[DVDT_OFF + idx] = (f_acc[idx] - c * vv * mi) / mi;
        out[V_OFF + idx] = vv;
        ke += 0.5f * mi * vv * vv;
    }
    red[t] = ke;
    __syncthreads();
    for (int s = 128; s > 0; s >>= 1) {
        if (t < s) red[t] += red[t + s];
        __syncthreads();
    }
    if (t == 0) {
        float k0 = red[0];
        float e0 = p_eta[0], e1 = p_eta[1], e2 = p_eta[2], e3 = p_eta[3];
        out[PETA_OFF + 0] = 2.f * (k0 - TARGET_KE) - e0 * e1 / QI_F;
        out[PETA_OFF + 1] = e0 * e0 / Q0_F - KT_F - e1 * e2 / QI_F;
        out[PETA_OFF + 2] = e1 * e1 / QI_F - KT_F - e2 * e3 / QI_F;
        out[PETA_OFF + 3] = e2 * e2 / QI_F - KT_F;
    }
}

// ---------------------------------------------------------------- launch
extern "C" void kernel_launch(void* const* d_in, const int* in_sizes, int n_in,
                              void* d_out, int out_size, void* d_ws, size_t ws_size,
                              hipStream_t stream)
{
    const float* v     = (const float*)d_in[0];
    const float* q     = (const float*)d_in[1];
    const float* p_eta = (const float*)d_in[2];
    const float* mass  = (const float*)d_in[3];
    const float* embed = (const float*)d_in[4];
    const float* W1    = (const float*)d_in[5];
    const float* b1    = (const float*)d_in[6];
    const float* W2    = (const float*)d_in[7];
    const float* b2    = (const float*)d_in[8];
    const float* W3    = (const float*)d_in[9];
    const float* wout  = (const float*)d_in[10];
    const int*   z     = (const int*)d_in[11];
    float* out = (float*)d_out;

    float* h     = (float*)d_ws;            // 98304 floats? -> N*F
    float* W3T   = h + N_ATOMS * FD;        // 16384
    float* f_acc = W3T + FD * FD;           // 2304
    int* nbr_cnt = (int*)(f_acc + 3 * N_ATOMS);  // 768
    int* nbr_idx = nbr_cnt + N_ATOMS;            // 768*96

    prep_nbr_kernel<<<N_ATOMS, 256, 0, stream>>>(q, z, embed, W3, h, W3T,
                                                 f_acc, nbr_cnt, nbr_idx);
    schnet_kernel<<<N_ATOMS, 256, 0, stream>>>(q, W1, b1, W2, b2, h, W3, W3T,
                                               wout, nbr_cnt, nbr_idx, f_acc);
    fin_kernel<<<1, 256, 0, stream>>>(v, mass, p_eta, f_acc, out);
}

// Round 5
// 218.272 us; speedup vs baseline: 1.2067x; 1.1225x over previous
//
#include <hip/hip_runtime.h>
#include <math.h>

// Problem constants (match reference)
#define N_ATOMS 768
#define FD 128          // feature width
#define NRBF 32
#define MAXN 64         // per-atom neighbor cap (mean ~26, max ~50)
#define PPB 64          // pairs per block in fwd/bwd
#define NPB (N_ATOMS * MAXN / PPB)   // 768 grid blocks (covers worst case)
#define AST 132         // padded LDS stride for [64][128] tiles (132*4B, 16B-aligned, +4 breaks bank stride)
#define RST 36          // padded LDS stride for [64][32] rbf tiles

constexpr float  CUT2   = 25.0f;
constexpr float  GAMMA_ = 40.96f;            // 1/(5/32)^2
constexpr float  CSTEP  = 5.0f / 31.0f;      // linspace(0,5,32) step
constexpr double KB_D   = 8.617330337217213e-05;
constexpr double KT_D   = 300.0 * KB_D;
constexpr float  KT_F   = (float)KT_D;
constexpr float  TARGET_KE = (float)(0.5 * 2304.0 * KT_D);
constexpr float  Q0_F   = (float)(2.0 * 2304.0 * KT_D * 400.0);  // Q[0]
constexpr float  QI_F   = (float)(2.0 * KT_D * 400.0);           // Q[1..3]

#define DVDT_OFF 0
#define V_OFF    (3 * N_ATOMS)
#define PETA_OFF (6 * N_ATOMS)

// ---------------------------------------------------------------- prep:
// per-atom neighbor scan -> flat compacted pair list (i-runs contiguous via
// one atomic reservation per atom). Also h gather + W2T/W3T transposes.
__global__ __launch_bounds__(256) void prep_kernel(
    const float* __restrict__ q, const int* __restrict__ z,
    const float* __restrict__ embed, const float* __restrict__ W2,
    const float* __restrict__ W3,
    float* __restrict__ h, float* __restrict__ W2T, float* __restrict__ W3T,
    int* __restrict__ pair_i, int* __restrict__ pair_j,
    float* __restrict__ pair_d, float* __restrict__ pair_dx,
    float* __restrict__ pair_dy, float* __restrict__ pair_dz,
    int* __restrict__ npairs_ctr)
{
    __shared__ int   nj[MAXN];
    __shared__ float nd[MAXN], ndx[MAXN], ndy[MAXN], ndz[MAXN];
    __shared__ int cnt_s, base_s;
    int i = blockIdx.x, t = threadIdx.x;
    if (t == 0) cnt_s = 0;
    __syncthreads();
    float qx = q[i*3], qy = q[i*3+1], qz = q[i*3+2];
    for (int j = t; j < N_ATOMS; j += 256) {
        if (j == i) continue;
        float dx = qx - q[j*3], dy = qy - q[j*3+1], dz = qz - q[j*3+2];
        float d2 = dx*dx + dy*dy + dz*dz;
        if (d2 < CUT2) {
            int p = atomicAdd(&cnt_s, 1);
            if (p < MAXN) { nj[p] = j; nd[p] = sqrtf(d2);
                            ndx[p] = dx; ndy[p] = dy; ndz[p] = dz; }
        }
    }
    // side tasks spread by global id
    int g = i * 256 + t;
    if (g < N_ATOMS * FD) h[g] = embed[z[g >> 7] * FD + (g & 127)];
    int g2 = g - N_ATOMS * FD;
    if (g2 >= 0 && g2 < FD * FD) {
        int r = g2 >> 7, c = g2 & 127;
        W2T[c * FD + r] = W2[g2];
        W3T[c * FD + r] = W3[g2];
    }
    __syncthreads();
    if (t == 0) base_s = atomicAdd(npairs_ctr, min(cnt_s, MAXN));
    __syncthreads();
    int cnt = min(cnt_s, MAXN), base = base_s;
    if (t < cnt) {
        pair_i[base+t] = i;      pair_j[base+t] = nj[t];
        pair_d[base+t] = nd[t];  pair_dx[base+t] = ndx[t];
        pair_dy[base+t] = ndy[t]; pair_dz[base+t] = ndz[t];
    }
}

// ---------------------------------------------------------------- fwd:
// block = 64 pairs.  rbf tile -> a1 tile (LDS) -> a1 @ W2 (register-tiled,
// thread owns 8 pairs x 4 cols) -> m[i] += filt (.) h[j]  (segmented atomics).
__global__ __launch_bounds__(256, 3) void fwd_kernel(
    const float* __restrict__ W1, const float* __restrict__ b1,
    const float* __restrict__ W2, const float* __restrict__ b2,
    const float* __restrict__ h,
    const int* __restrict__ pair_i, const int* __restrict__ pair_j,
    const float* __restrict__ pair_d, const int* __restrict__ npairs_ctr,
    float* __restrict__ m)
{
    __shared__ float rbf_s[PPB * RST];   //  9216 B
    __shared__ float a1_s[PPB * AST];    // 33792 B
    __shared__ int   pis[PPB], pjs[PPB]; //   512 B
    int t = threadIdx.x;
    int base = blockIdx.x * PPB;
    int np = npairs_ctr[0];
    if (base >= np) return;

    if (t < PPB) {
        int p = base + t; bool ok = p < np;
        pis[t] = ok ? pair_i[p] : 0;
        pjs[t] = ok ? pair_j[p] : 0;
    }
    for (int idx = t; idx < PPB * NRBF; idx += 256) {
        int p = idx >> 5, k = idx & 31;
        int gp = base + p;
        float d = (gp < np) ? pair_d[gp] : 1.0f;
        float u = d - CSTEP * (float)k;
        rbf_s[p * RST + k] = __expf(-GAMMA_ * u * u);
    }
    __syncthreads();

    // GEMM-1: a1[p][c] = relu(b1[c] + rbf[p]@W1[:,c]); thread = (c, half-of-pairs)
    {
        int c = t & 127, ph = t >> 7;
        float w1c[NRBF];
#pragma unroll
        for (int k = 0; k < NRBF; k++) w1c[k] = W1[k * FD + c];
        float b1c = b1[c];
        for (int p = ph * 32; p < ph * 32 + 32; p++) {
            float u = b1c;
#pragma unroll
            for (int k4 = 0; k4 < NRBF / 4; k4++) {
                float4 r = *(const float4*)(rbf_s + p * RST + k4 * 4);
                u += r.x*w1c[k4*4] + r.y*w1c[k4*4+1] + r.z*w1c[k4*4+2] + r.w*w1c[k4*4+3];
            }
            a1_s[p * AST + c] = fmaxf(u, 0.f);
        }
    }
    __syncthreads();

    // GEMM-2: filt[p][c] = a1[p]@W2[:,c] + b2[c]
    int st = t >> 5, cg = t & 31, c4 = 4 * cg;
    float acc[8][4];
#pragma unroll
    for (int e = 0; e < 8; e++) { acc[e][0]=0; acc[e][1]=0; acc[e][2]=0; acc[e][3]=0; }
    for (int k = 0; k < FD; k += 4) {
        float4 w0 = *(const float4*)(W2 + (k+0) * FD + c4);
        float4 w1v= *(const float4*)(W2 + (k+1) * FD + c4);
        float4 w2v= *(const float4*)(W2 + (k+2) * FD + c4);
        float4 w3v= *(const float4*)(W2 + (k+3) * FD + c4);
#pragma unroll
        for (int e = 0; e < 8; e++) {
            float4 a = *(const float4*)(a1_s + (st*8+e) * AST + k);
            acc[e][0] += a.x*w0.x + a.y*w1v.x + a.z*w2v.x + a.w*w3v.x;
            acc[e][1] += a.x*w0.y + a.y*w1v.y + a.z*w2v.y + a.w*w3v.y;
            acc[e][2] += a.x*w0.z + a.y*w1v.z + a.z*w2v.z + a.w*w3v.z;
            acc[e][3] += a.x*w0.w + a.y*w1v.w + a.z*w2v.w + a.w*w3v.w;
        }
    }
    // epilogue: m[i] += (filt) (.) h[j], run-segmented per thread
    float4 b2v = *(const float4*)(b2 + c4);
    float r0 = 0, r1 = 0, r2 = 0, r3 = 0;
    int cur_i = pis[st * 8];
#pragma unroll
    for (int e = 0; e < 8; e++) {
        int lp = st * 8 + e, gp = base + lp;
        int ip = pis[lp];
        if (ip != cur_i) {
            atomicAdd(m + cur_i*FD + c4 + 0, r0);
            atomicAdd(m + cur_i*FD + c4 + 1, r1);
            atomicAdd(m + cur_i*FD + c4 + 2, r2);
            atomicAdd(m + cur_i*FD + c4 + 3, r3);
            r0 = r1 = r2 = r3 = 0; cur_i = ip;
        }
        if (gp < np) {
            float4 hj = *(const float4*)(h + pjs[lp] * FD + c4);
            r0 += (acc[e][0] + b2v.x) * hj.x;
            r1 += (acc[e][1] + b2v.y) * hj.y;
            r2 += (acc[e][2] + b2v.z) * hj.z;
            r3 += (acc[e][3] + b2v.w) * hj.w;
        }
    }
    atomicAdd(m + cur_i*FD + c4 + 0, r0);
    atomicAdd(m + cur_i*FD + c4 + 1, r1);
    atomicAdd(m + cur_i*FD + c4 + 2, r2);
    atomicAdd(m + cur_i*FD + c4 + 3, r3);
}

// ---------------------------------------------------------------- mbar (per atom)
__global__ __launch_bounds__(128) void mbar_kernel(
    const float* __restrict__ m, const float* __restrict__ W3,
    const float* __restrict__ W3T, const float* __restrict__ w_out,
    float* __restrict__ mbar)
{
    __shared__ float ms[FD];
    __shared__ float gb[FD];
    int i = blockIdx.x, t = threadIdx.x;
    ms[t] = m[i * FD + t];
    __syncthreads();
    float g = 0.f;
#pragma unroll 8
    for (int f = 0; f < FD; f++) g += ms[f] * W3[f * FD + t];
    gb[t] = (g > 0.f) ? w_out[t] : 0.f;
    __syncthreads();
    float mb = 0.f;
#pragma unroll 8
    for (int c = 0; c < FD; c++) mb += gb[c] * W3T[c * FD + t];
    mbar[i * FD + t] = mb;
}

// ---------------------------------------------------------------- bwd:
// block = 64 pairs.  t-tile = mbar_i (.) h_j -> du1 = t @ W2T (same GEMM
// skeleton) -> epilogue recomputes gate(u1) and e = crbf@W1 in-register,
// s_ij = sum_c gate*du1*e, shuffle-reduce, 6 atomics per pair.
__global__ __launch_bounds__(256, 3) void bwd_kernel(
    const float* __restrict__ W1, const float* __restrict__ b1,
    const float* __restrict__ W2T, const float* __restrict__ h,
    const float* __restrict__ mbar,
    const int* __restrict__ pair_i, const int* __restrict__ pair_j,
    const float* __restrict__ pair_d, const float* __restrict__ pair_dx,
    const float* __restrict__ pair_dy, const float* __restrict__ pair_dz,
    const int* __restrict__ npairs_ctr, float* __restrict__ f_acc)
{
    __shared__ float rbf_s[PPB * RST];    //  9216 B
    __shared__ float crbf_s[PPB * RST];   //  9216 B
    __shared__ float ts[PPB * AST];       // 33792 B
    __shared__ int   pis[PPB], pjs[PPB];  //   512 B   (total 52736 B -> 3/CU)
    int t = threadIdx.x;
    int base = blockIdx.x * PPB;
    int np = npairs_ctr[0];
    if (base >= np) return;

    if (t < PPB) {
        int p = base + t; bool ok = p < np;
        pis[t] = ok ? pair_i[p] : 0;
        pjs[t] = ok ? pair_j[p] : 0;
    }
    for (int idx = t; idx < PPB * NRBF; idx += 256) {
        int p = idx >> 5, k = idx & 31;
        int gp = base + p;
        float d = (gp < np) ? pair_d[gp] : 1.0f;
        float u = d - CSTEP * (float)k;
        float r = __expf(-GAMMA_ * u * u);
        rbf_s[p * RST + k]  = r;
        crbf_s[p * RST + k] = -2.f * GAMMA_ * u * r;
    }
    __syncthreads();                       // pis/pjs ready
    for (int idx = t; idx < PPB * FD; idx += 256) {
        int p = idx >> 7, c = idx & 127;
        ts[p * AST + c] = mbar[pis[p] * FD + c] * h[pjs[p] * FD + c];
    }
    __syncthreads();

    // GEMM-2': du1[p][c] = t[p] @ W2T[:,c]
    int st = t >> 5, cg = t & 31, c4 = 4 * cg;
    float acc[8][4];
#pragma unroll
    for (int e = 0; e < 8; e++) { acc[e][0]=0; acc[e][1]=0; acc[e][2]=0; acc[e][3]=0; }
    for (int k = 0; k < FD; k += 4) {
        float4 w0 = *(const float4*)(W2T + (k+0) * FD + c4);
        float4 w1v= *(const float4*)(W2T + (k+1) * FD + c4);
        float4 w2v= *(const float4*)(W2T + (k+2) * FD + c4);
        float4 w3v= *(const float4*)(W2T + (k+3) * FD + c4);
#pragma unroll
        for (int e = 0; e < 8; e++) {
            float4 a = *(const float4*)(ts + (st*8+e) * AST + k);
            acc[e][0] += a.x*w0.x + a.y*w1v.x + a.z*w2v.x + a.w*w3v.x;
            acc[e][1] += a.x*w0.y + a.y*w1v.y + a.z*w2v.y + a.w*w3v.y;
            acc[e][2] += a.x*w0.z + a.y*w1v.z + a.z*w2v.z + a.w*w3v.z;
            acc[e][3] += a.x*w0.w + a.y*w1v.w + a.z*w2v.w + a.w*w3v.w;
        }
    }
    // epilogue: two groups of 4 pairs (register diet)
    float4 b1v = *(const float4*)(b1 + c4);
    float sp[8];
#pragma unroll
    for (int eg = 0; eg < 2; eg++) {
        float4 u1[4], ef[4];
#pragma unroll
        for (int ei = 0; ei < 4; ei++) { u1[ei] = b1v; ef[ei] = make_float4(0,0,0,0); }
#pragma unroll
        for (int k4 = 0; k4 < NRBF / 4; k4++) {
            float4 wA = *(const float4*)(W1 + (k4*4+0) * FD + c4);
            float4 wB = *(const float4*)(W1 + (k4*4+1) * FD + c4);
            float4 wC = *(const float4*)(W1 + (k4*4+2) * FD + c4);
            float4 wD = *(const float4*)(W1 + (k4*4+3) * FD + c4);
#pragma unroll
            for (int ei = 0; ei < 4; ei++) {
                int lp = st * 8 + eg * 4 + ei;
                float4 r = *(const float4*)(rbf_s  + lp * RST + k4 * 4);
                float4 cd= *(const float4*)(crbf_s + lp * RST + k4 * 4);
                u1[ei].x += r.x*wA.x + r.y*wB.x + r.z*wC.x + r.w*wD.x;
                u1[ei].y += r.x*wA.y + r.y*wB.y + r.z*wC.y + r.w*wD.y;
                u1[ei].z += r.x*wA.z + r.y*wB.z + r.z*wC.z + r.w*wD.z;
                u1[ei].w += r.x*wA.w + r.y*wB.w + r.z*wC.w + r.w*wD.w;
                ef[ei].x += cd.x*wA.x + cd.y*wB.x + cd.z*wC.x + cd.w*wD.x;
                ef[ei].y += cd.x*wA.y + cd.y*wB.y + cd.z*wC.y + cd.w*wD.y;
                ef[ei].z += cd.x*wA.z + cd.y*wB.z + cd.z*wC.z + cd.w*wD.z;
                ef[ei].w += cd.x*wA.w + cd.y*wB.w + cd.z*wC.w + cd.w*wD.w;
            }
        }
#pragma unroll
        for (int ei = 0; ei < 4; ei++) {
            int e = eg * 4 + ei;
            float s = ((u1[ei].x > 0.f) ? acc[e][0] : 0.f) * ef[ei].x
                    + ((u1[ei].y > 0.f) ? acc[e][1] : 0.f) * ef[ei].y
                    + ((u1[ei].z > 0.f) ? acc[e][2] : 0.f) * ef[ei].z
                    + ((u1[ei].w > 0.f) ? acc[e][3] : 0.f) * ef[ei].w;
#pragma unroll
            for (int off = 1; off < 32; off <<= 1) s += __shfl_xor(s, off, 64);
            sp[e] = s;
        }
    }
    if (cg == 0) {
#pragma unroll
        for (int e = 0; e < 8; e++) {
            int lp = st * 8 + e, gp = base + lp;
            if (gp < np) {
                int ii = pis[lp], jj = pjs[lp];
                float coef = sp[e] / pair_d[gp];
                float fx = coef * pair_dx[gp];
                float fy = coef * pair_dy[gp];
                float fz = coef * pair_dz[gp];
                atomicAdd(f_acc + ii*3 + 0, -fx);
                atomicAdd(f_acc + ii*3 + 1, -fy);
                atomicAdd(f_acc + ii*3 + 2, -fz);
                atomicAdd(f_acc + jj*3 + 0, fx);
                atomicAdd(f_acc + jj*3 + 1, fy);
                atomicAdd(f_acc + jj*3 + 2, fz);
            }
        }
    }
}

// ---------------------------------------------------------------- finalize
__global__ __launch_bounds__(256) void fin_kernel(
    const float* __restrict__ v, const float* __restrict__ mass,
    const float* __restrict__ p_eta, const float* __restrict__ f_acc,
    float* __restrict__ out)
{
    __shared__ float red[256];
    int t = threadIdx.x;
    float ke = 0.f;
    float c = p_eta[0] / Q0_F;
    for (int idx = t; idx < 3 * N_ATOMS; idx += 256) {
        int a = idx / 3;
        float vv = v[idx], mi = mass[a];
        out[DVDT_OFF + idx] = (f_acc[idx] - c * vv * mi) / mi;
        out[V_OFF + idx] = vv;
        ke += 0.5f * mi * vv * vv;
    }
    red[t] = ke;
    __syncthreads();
    for (int s = 128; s > 0; s >>= 1) {
        if (t < s) red[t] += red[t + s];
        __syncthreads();
    }
    if (t == 0) {
        float k0 = red[0];
        float e0 = p_eta[0], e1 = p_eta[1], e2 = p_eta[2], e3 = p_eta[3];
        out[PETA_OFF + 0] = 2.f * (k0 - TARGET_KE) - e0 * e1 / QI_F;
        out[PETA_OFF + 1] = e0 * e0 / Q0_F - KT_F - e1 * e2 / QI_F;
        out[PETA_OFF + 2] = e1 * e1 / QI_F - KT_F - e2 * e3 / QI_F;
        out[PETA_OFF + 3] = e2 * e2 / QI_F - KT_F;
    }
}

// ---------------------------------------------------------------- launch
extern "C" void kernel_launch(void* const* d_in, const int* in_sizes, int n_in,
                              void* d_out, int out_size, void* d_ws, size_t ws_size,
                              hipStream_t stream)
{
    const float* v     = (const float*)d_in[0];
    const float* q     = (const float*)d_in[1];
    const float* p_eta = (const float*)d_in[2];
    const float* mass  = (const float*)d_in[3];
    const float* embed = (const float*)d_in[4];
    const float* W1    = (const float*)d_in[5];
    const float* b1    = (const float*)d_in[6];
    const float* W2    = (const float*)d_in[7];
    const float* b2    = (const float*)d_in[8];
    const float* W3    = (const float*)d_in[9];
    const float* wout  = (const float*)d_in[10];
    const int*   z     = (const int*)d_in[11];
    float* out = (float*)d_out;

    float* h     = (float*)d_ws;                 // 98304
    float* W2T   = h + N_ATOMS * FD;             // 16384
    float* W3T   = W2T + FD * FD;                // 16384
    float* m     = W3T + FD * FD;                // 98304
    float* mbar  = m + N_ATOMS * FD;             // 98304
    float* f_acc = mbar + N_ATOMS * FD;          // 2304
    float* pair_d  = f_acc + 3 * N_ATOMS;        // 49152
    float* pair_dx = pair_d + N_ATOMS * MAXN;    // 49152
    float* pair_dy = pair_dx + N_ATOMS * MAXN;   // 49152
    float* pair_dz = pair_dy + N_ATOMS * MAXN;   // 49152
    int* pair_i = (int*)(pair_dz + N_ATOMS * MAXN);  // 49152
    int* pair_j = pair_i + N_ATOMS * MAXN;           // 49152
    int* npairs_ctr = pair_j + N_ATOMS * MAXN;       // 1

    hipMemsetAsync(npairs_ctr, 0, sizeof(int), stream);
    hipMemsetAsync(f_acc, 0, 3 * N_ATOMS * sizeof(float), stream);
    hipMemsetAsync(m, 0, N_ATOMS * FD * sizeof(float), stream);

    prep_kernel<<<N_ATOMS, 256, 0, stream>>>(q, z, embed, W2, W3, h, W2T, W3T,
                                             pair_i, pair_j, pair_d,
                                             pair_dx, pair_dy, pair_dz, npairs_ctr);
    fwd_kernel<<<NPB, 256, 0, stream>>>(W1, b1, W2, b2, h, pair_i, pair_j,
                                        pair_d, npairs_ctr, m);
    mbar_kernel<<<N_ATOMS, 128, 0, stream>>>(m, W3, W3T, wout, mbar);
    bwd_kernel<<<NPB, 256, 0, stream>>>(W1, b1, W2T, h, mbar, pair_i, pair_j,
                                        pair_d, pair_dx, pair_dy, pair_dz,
                                        npairs_ctr, f_acc);
    fin_kernel<<<1, 256, 0, stream>>>(v, mass, p_eta, f_acc, out);
}